// Round 2
// baseline (3195.974 us; speedup 1.0000x reference)
//
#include <hip/hip_runtime.h>
#include <hip/hip_bf16.h>

typedef unsigned int u32;
typedef _Float16     f16;
typedef f16   f16x8v __attribute__((ext_vector_type(8)));
typedef float f32x4  __attribute__((ext_vector_type(4)));

#define GX_BYTES ((size_t)65536 * 1024 * 2)

__device__ __forceinline__ float sigm(float x) {
    return __builtin_amdgcn_rcpf(1.0f + __expf(-x));
}
__device__ __forceinline__ float tanh_f(float x) {
    return 1.0f - 2.0f * __builtin_amdgcn_rcpf(__expf(2.0f * x) + 1.0f);
}
__device__ __forceinline__ f16x8v pack8(float4 a, float4 b) {
    f16x8v v;
    v[0] = (f16)a.x; v[1] = (f16)a.y; v[2] = (f16)a.z; v[3] = (f16)a.w;
    v[4] = (f16)b.x; v[5] = (f16)b.y; v[6] = (f16)b.z; v[7] = (f16)b.w;
    return v;
}

// ---------------------------------------------------------------------------
// Kernel 1: gates_x = x @ Wg[:, :256]^T + bg  -> f16 [65536][1024]
// (unchanged — plus zeroing the 256 KB mailbox each replay so stale tags
//  can never satisfy this run's polls)
// ---------------------------------------------------------------------------
__global__ __launch_bounds__(256) void gemm_gx(
    const float* __restrict__ X,
    const float* __restrict__ Wf, const float* __restrict__ Wi,
    const float* __restrict__ Wc, const float* __restrict__ Wo,
    const float* __restrict__ bf_, const float* __restrict__ bi_,
    const float* __restrict__ bc_, const float* __restrict__ bo_,
    f16* __restrict__ gx, u32* __restrict__ hx) {
    __shared__ _Float16 As[128 * 40];
    __shared__ _Float16 Bs[128 * 40];
    __shared__ float bias_lds[128];

    const int tid = threadIdx.x;
    const int wgy = blockIdx.y;
    const size_t m0 = (size_t)blockIdx.x * 128;

    if (wgy == 0) {
        const int gid = blockIdx.x * 256 + tid;
        if (gid < 16384) {
            int4 z; z.x = 0; z.y = 0; z.z = 0; z.w = 0;
            ((int4*)hx)[gid] = z;
        }
    }

    const float* Wsel[4] = {Wf, Wi, Wc, Wo};
    const float* bsel[4] = {bf_, bi_, bc_, bo_};
    const float* Wseg = Wsel[wgy >> 1];
    const int row_off = (wgy & 1) * 128;

    if (tid < 128) bias_lds[tid] = bsel[wgy >> 1][row_off + tid];

    const int r  = tid >> 2;
    const int c8 = (tid & 3) * 8;

    const float* Ap0 = X + (m0 + r) * 256 + c8;
    const float* Ap1 = Ap0 + 64 * 256;
    const float* Bp0 = Wseg + (size_t)(row_off + r) * 512 + c8;
    const float* Bp1 = Bp0 + 64 * 512;

    const int lane = tid & 63;
    const int w    = tid >> 6;
    const int wm = w >> 1, wn = w & 1;
    const int col = lane & 15, quad = lane >> 4;

    f32x4 acc[4][4] = {};

    for (int kc = 0; kc < 8; kc++) {
        const int kk = kc * 32;
        float4 a00 = *(const float4*)(Ap0 + kk);
        float4 a01 = *(const float4*)(Ap0 + kk + 4);
        float4 a10 = *(const float4*)(Ap1 + kk);
        float4 a11 = *(const float4*)(Ap1 + kk + 4);
        float4 b00 = *(const float4*)(Bp0 + kk);
        float4 b01 = *(const float4*)(Bp0 + kk + 4);
        float4 b10 = *(const float4*)(Bp1 + kk);
        float4 b11 = *(const float4*)(Bp1 + kk + 4);
        __syncthreads();
        *(f16x8v*)&As[r * 40 + c8]        = pack8(a00, a01);
        *(f16x8v*)&As[(r + 64) * 40 + c8] = pack8(a10, a11);
        *(f16x8v*)&Bs[r * 40 + c8]        = pack8(b00, b01);
        *(f16x8v*)&Bs[(r + 64) * 40 + c8] = pack8(b10, b11);
        __syncthreads();
        f16x8v a[4], b[4];
        #pragma unroll
        for (int i = 0; i < 4; i++)
            a[i] = *(const f16x8v*)&As[(wm * 64 + i * 16 + col) * 40 + quad * 8];
        #pragma unroll
        for (int j = 0; j < 4; j++)
            b[j] = *(const f16x8v*)&Bs[(wn * 64 + j * 16 + col) * 40 + quad * 8];
        #pragma unroll
        for (int i = 0; i < 4; i++)
            #pragma unroll
            for (int j = 0; j < 4; j++)
                acc[i][j] = __builtin_amdgcn_mfma_f32_16x16x32_f16(a[i], b[j], acc[i][j], 0, 0, 0);
    }

    #pragma unroll
    for (int i = 0; i < 4; i++) {
        #pragma unroll
        for (int j = 0; j < 4; j++) {
            #pragma unroll
            for (int rg = 0; rg < 4; rg++) {
                const size_t m = m0 + wm * 64 + i * 16 + quad * 4 + rg;
                const int nl = wn * 64 + j * 16 + col;
                gx[m * 1024 + (size_t)wgy * 128 + nl] = (f16)(acc[i][j][rg] + bias_lds[nl]);
            }
        }
    }
}

// ---------------------------------------------------------------------------
// Kernel 2: batch-packed recurrence. 128 WGs x 256 thr.
// WG (g = blk&7, j = blk>>3) owns batch-group g (batches 16g..16g+16) and
// unit-slice j (units 16j..16j+16). Per step: H[16,256] @ Wh_slice^T[256,64]
// = 4 gate-tiles x 8-MFMA K-chain = 32 MFMAs/WG (16x less chip-wide MFMA
// than the replicated-row scheme — A rows now hold 16 DISTINCT batches).
// Wave w computes gate w; gates combined via a 4 KB LDS buffer; thread
// (b_loc = tid>>4, u_loc = tid&15) owns one (batch,unit) c/h cell.
//
// Cross-WG exchange (all-to-all within the 16 WGs of a group): tagged-word
// mailbox, (h<<16)|(t+1), relaxed agent-scope atomics, 2-slot double buffer.
// Safety induction: WG A overwrites its tag-(t-1) words with tag-(t+1) only
// after A's poll of tag t succeeded, which required every peer B to publish
// tag t, which (barrier2 at each iteration end) is after ALL of B's tag-(t-1)
// polls completed. g = blk&7 puts a group's 16 WGs on one XCD (locality).
// H staged into XOR-swizzled LDS (f16-idx col ^= (row&7)<<3) so batch-major
// ds_read_b128 A-fragments don't 16-way bank-conflict.
// ---------------------------------------------------------------------------
__global__ __launch_bounds__(256) void lstm_rec(
    const float* __restrict__ Wf, const float* __restrict__ Wi,
    const float* __restrict__ Wc, const float* __restrict__ Wo,
    const f16* __restrict__ gx,
    const float* __restrict__ Wout, const float* __restrict__ bout,
    u32* hx,
    float* __restrict__ out) {
    __shared__ _Float16 hbuf[2][16 * 256] __attribute__((aligned(16)));
    __shared__ float gates_lds[4][16][16];

    const int tid  = threadIdx.x;
    const int bb   = blockIdx.x;
    const int g    = bb & 7;          // batch-group (same XCD for all 16 WGs)
    const int j    = bb >> 3;         // unit-slice 0..15
    const int w    = tid >> 6;        // wave = gate (f,i,c,o)
    const int l    = tid & 63;
    const int l15  = l & 15;
    const int quad = l >> 4;

    const int b_loc = tid >> 4;       // 0..15 batch within group
    const int u_loc = tid & 15;       // 0..15 unit within slice
    const int u_abs = j * 16 + u_loc; // absolute unit
    const int b_abs = g * 16 + b_loc; // absolute batch

    // --- register-resident B fragments for gate w: unit = 16j + l15 ---
    f16x8v wB[8];
    {
        const float* gp[4] = {Wf, Wi, Wc, Wo};
        const float* row = gp[w] + (size_t)(j * 16 + l15) * 512 + 256 + quad * 8;
        #pragma unroll
        for (int kt = 0; kt < 8; kt++) {
            float4 x0 = *(const float4*)(row + kt * 32);
            float4 x1 = *(const float4*)(row + kt * 32 + 4);
            wB[kt] = pack8(x0, x1);
        }
    }

    // H_0 = 0
    {
        f16x8v z = {};
        *(f16x8v*)&hbuf[0][tid * 16]     = z;
        *(f16x8v*)&hbuf[0][tid * 16 + 8] = z;
    }

    float c = 0.0f;

    u32* mail = hx + (size_t)g * 2 * 4096;      // [slot][16 batch][256 unit]
    const int pb  = tid >> 4;                   // batch row this thread polls
    const int pu0 = (tid & 15) * 16;            // 16 units polled

    const f16* gxr = gx + ((size_t)b_abs * 512) * 1024 + u_abs;
    float pf  = (float)gxr[0];
    float pi_ = (float)gxr[256];
    float pg  = (float)gxr[512];
    float po  = (float)gxr[768];

    const f32x4 Zc = {0.f, 0.f, 0.f, 0.f};

    __syncthreads();   // H_0 visible

    int cur = 0;
    for (int t = 0; t < 512; t++) {
        float gf = pf, gi = pi_, gg = pg, go = po;
        {   // branchless prefetch of next step's x-gates
            const f16* gn = gxr + (size_t)(t < 511 ? t + 1 : 511) * 1024;
            pf  = (float)gn[0];
            pi_ = (float)gn[256];
            pg  = (float)gn[512];
            po  = (float)gn[768];
        }

        // --- gate w: C[16 batch][16 unit] = H[16,256] @ Wg_slice^T ---
        f32x4 acc;
        {
            const int r3 = l15 & 7;
            #pragma unroll
            for (int kt = 0; kt < 8; kt++) {
                const int col = (kt * 32 + quad * 8) ^ (r3 << 3);
                f16x8v A = *(const f16x8v*)&hbuf[cur][l15 * 256 + col];
                if (kt == 0)
                    acc = __builtin_amdgcn_mfma_f32_16x16x32_f16(A, wB[0], Zc, 0, 0, 0);
                else
                    acc = __builtin_amdgcn_mfma_f32_16x16x32_f16(A, wB[kt], acc, 0, 0, 0);
            }
        }
        // C layout: col=l15 (unit), row=quad*4+r (batch)
        #pragma unroll
        for (int r = 0; r < 4; r++)
            gates_lds[w][quad * 4 + r][l15] = acc[r];

        __syncthreads();   // gates visible

        float F = gf + gates_lds[0][b_loc][u_loc];
        float I = gi + gates_lds[1][b_loc][u_loc];
        float G = gg + gates_lds[2][b_loc][u_loc];
        float O = go + gates_lds[3][b_loc][u_loc];
        float sf = sigm(F), si = sigm(I), so = sigm(O);
        float tg = tanh_f(G);
        c = c * sf + si * tg;
        float h = tanh_f(c) * so;

        const int ns = (t + 1) & 1;
        u32* slot = mail + (size_t)ns * 4096;
        {
            const f16 h16v = (f16)h;
            u32 word = ((u32)__builtin_bit_cast(unsigned short, h16v) << 16)
                     | (u32)(t + 1);
            __hip_atomic_store(slot + b_loc * 256 + u_abs, word,
                               __ATOMIC_RELAXED, __HIP_MEMORY_SCOPE_AGENT);
        }

        // poll: this thread gathers 16 units of batch row pb
        u32 wd[16];
        {
            u32* pp = slot + pb * 256 + pu0;
            const u32 want = (u32)(t + 1);
            int spin = 0;
            for (;;) {
                int ok = 1;
                #pragma unroll
                for (int e = 0; e < 16; e++) {
                    wd[e] = __hip_atomic_load(pp + e, __ATOMIC_RELAXED,
                                              __HIP_MEMORY_SCOPE_AGENT);
                    ok &= ((wd[e] & 0xFFFFu) == want);
                }
                if (__all(ok) || ++spin > (1 << 20)) break;   // never hang
            }
        }
        // stage into swizzled H LDS
        {
            f16x8v v0, v1;
            #pragma unroll
            for (int e = 0; e < 8; e++) {
                v0[e] = __builtin_bit_cast(_Float16, (unsigned short)(wd[e]     >> 16));
                v1[e] = __builtin_bit_cast(_Float16, (unsigned short)(wd[e + 8] >> 16));
            }
            const int r3p = pb & 7;
            *(f16x8v*)&hbuf[ns][pb * 256 + ((pu0    ) ^ (r3p << 3))] = v0;
            *(f16x8v*)&hbuf[ns][pb * 256 + ((pu0 + 8) ^ (r3p << 3))] = v1;
        }

        __syncthreads();   // H_{t+1} staged; also guards hbuf/gates reuse
        cur = ns;
    }

    // out[b_abs, :] = h_512 @ Wout^T + bout ; thread: batch b_loc, 8 outputs
    {
        const int o0 = u_loc * 8;
        float accs[8];
        #pragma unroll
        for (int r = 0; r < 8; r++) accs[r] = bout[o0 + r];
        const int r3 = b_loc & 7;
        for (int k0 = 0; k0 < 256; k0 += 8) {
            f16x8v hv = *(const f16x8v*)&hbuf[0][b_loc * 256 + (k0 ^ (r3 << 3))];
            float hf[8];
            #pragma unroll
            for (int e = 0; e < 8; e++) hf[e] = (float)hv[e];
            #pragma unroll
            for (int r = 0; r < 8; r++) {
                const float* wr = Wout + (size_t)(o0 + r) * 256 + k0;
                float4 w0 = *(const float4*)(wr);
                float4 w1 = *(const float4*)(wr + 4);
                accs[r] += w0.x * hf[0] + w0.y * hf[1] + w0.z * hf[2] + w0.w * hf[3]
                         + w1.x * hf[4] + w1.y * hf[5] + w1.z * hf[6] + w1.w * hf[7];
            }
        }
        #pragma unroll
        for (int r = 0; r < 8; r++)
            out[(size_t)b_abs * 128 + o0 + r] = accs[r];
    }
}

extern "C" void kernel_launch(void* const* d_in, const int* in_sizes, int n_in,
                              void* d_out, int out_size, void* d_ws, size_t ws_size,
                              hipStream_t stream) {
    const float* x    = (const float*)d_in[0];
    const float* Wf   = (const float*)d_in[1];
    const float* bfv  = (const float*)d_in[2];
    const float* Wi   = (const float*)d_in[3];
    const float* biv  = (const float*)d_in[4];
    const float* Wc   = (const float*)d_in[5];
    const float* bcv  = (const float*)d_in[6];
    const float* Wo   = (const float*)d_in[7];
    const float* bov  = (const float*)d_in[8];
    const float* Wout = (const float*)d_in[9];
    const float* bout = (const float*)d_in[10];

    f16* gx = (f16*)d_ws;
    u32* hx = (u32*)((char*)d_ws + GX_BYTES);   // 256 KB mailbox after gx

    gemm_gx<<<dim3(512, 8), 256, 0, stream>>>(x, Wf, Wi, Wc, Wo, bfv, biv, bcv, bov, gx, hx);
    lstm_rec<<<128, 256, 0, stream>>>(Wf, Wi, Wc, Wo, gx, Wout, bout, hx, (float*)d_out);
}

// Round 3
// 2690.799 us; speedup vs baseline: 1.1877x; 1.1877x over previous
//
#include <hip/hip_runtime.h>
#include <hip/hip_bf16.h>

typedef unsigned int u32;
typedef _Float16     f16;
typedef f16   f16x8v __attribute__((ext_vector_type(8)));
typedef float f32x4  __attribute__((ext_vector_type(4)));

#define GX_BYTES ((size_t)65536 * 1024 * 2)

__device__ __forceinline__ float sigm(float x) {
    return __builtin_amdgcn_rcpf(1.0f + __expf(-x));
}
__device__ __forceinline__ float tanh_f(float x) {
    return 1.0f - 2.0f * __builtin_amdgcn_rcpf(__expf(2.0f * x) + 1.0f);
}
__device__ __forceinline__ f16x8v pack8(float4 a, float4 b) {
    f16x8v v;
    v[0] = (f16)a.x; v[1] = (f16)a.y; v[2] = (f16)a.z; v[3] = (f16)a.w;
    v[4] = (f16)b.x; v[5] = (f16)b.y; v[6] = (f16)b.z; v[7] = (f16)b.w;
    return v;
}

// ---------------------------------------------------------------------------
// Kernel 1: gates_x = x @ Wg[:, :256]^T + bg  -> f16 [65536][1024]
// (unchanged — plus zeroing the 256 KB mailbox each replay so stale tags
//  can never satisfy this run's polls)
// ---------------------------------------------------------------------------
__global__ __launch_bounds__(256) void gemm_gx(
    const float* __restrict__ X,
    const float* __restrict__ Wf, const float* __restrict__ Wi,
    const float* __restrict__ Wc, const float* __restrict__ Wo,
    const float* __restrict__ bf_, const float* __restrict__ bi_,
    const float* __restrict__ bc_, const float* __restrict__ bo_,
    f16* __restrict__ gx, u32* __restrict__ hx) {
    __shared__ _Float16 As[128 * 40];
    __shared__ _Float16 Bs[128 * 40];
    __shared__ float bias_lds[128];

    const int tid = threadIdx.x;
    const int wgy = blockIdx.y;
    const size_t m0 = (size_t)blockIdx.x * 128;

    if (wgy == 0) {
        const int gid = blockIdx.x * 256 + tid;
        if (gid < 16384) {
            int4 z; z.x = 0; z.y = 0; z.z = 0; z.w = 0;
            ((int4*)hx)[gid] = z;
        }
    }

    const float* Wsel[4] = {Wf, Wi, Wc, Wo};
    const float* bsel[4] = {bf_, bi_, bc_, bo_};
    const float* Wseg = Wsel[wgy >> 1];
    const int row_off = (wgy & 1) * 128;

    if (tid < 128) bias_lds[tid] = bsel[wgy >> 1][row_off + tid];

    const int r  = tid >> 2;
    const int c8 = (tid & 3) * 8;

    const float* Ap0 = X + (m0 + r) * 256 + c8;
    const float* Ap1 = Ap0 + 64 * 256;
    const float* Bp0 = Wseg + (size_t)(row_off + r) * 512 + c8;
    const float* Bp1 = Bp0 + 64 * 512;

    const int lane = tid & 63;
    const int w    = tid >> 6;
    const int wm = w >> 1, wn = w & 1;
    const int col = lane & 15, quad = lane >> 4;

    f32x4 acc[4][4] = {};

    for (int kc = 0; kc < 8; kc++) {
        const int kk = kc * 32;
        float4 a00 = *(const float4*)(Ap0 + kk);
        float4 a01 = *(const float4*)(Ap0 + kk + 4);
        float4 a10 = *(const float4*)(Ap1 + kk);
        float4 a11 = *(const float4*)(Ap1 + kk + 4);
        float4 b00 = *(const float4*)(Bp0 + kk);
        float4 b01 = *(const float4*)(Bp0 + kk + 4);
        float4 b10 = *(const float4*)(Bp1 + kk);
        float4 b11 = *(const float4*)(Bp1 + kk + 4);
        __syncthreads();
        *(f16x8v*)&As[r * 40 + c8]        = pack8(a00, a01);
        *(f16x8v*)&As[(r + 64) * 40 + c8] = pack8(a10, a11);
        *(f16x8v*)&Bs[r * 40 + c8]        = pack8(b00, b01);
        *(f16x8v*)&Bs[(r + 64) * 40 + c8] = pack8(b10, b11);
        __syncthreads();
        f16x8v a[4], b[4];
        #pragma unroll
        for (int i = 0; i < 4; i++)
            a[i] = *(const f16x8v*)&As[(wm * 64 + i * 16 + col) * 40 + quad * 8];
        #pragma unroll
        for (int j = 0; j < 4; j++)
            b[j] = *(const f16x8v*)&Bs[(wn * 64 + j * 16 + col) * 40 + quad * 8];
        #pragma unroll
        for (int i = 0; i < 4; i++)
            #pragma unroll
            for (int j = 0; j < 4; j++)
                acc[i][j] = __builtin_amdgcn_mfma_f32_16x16x32_f16(a[i], b[j], acc[i][j], 0, 0, 0);
    }

    #pragma unroll
    for (int i = 0; i < 4; i++) {
        #pragma unroll
        for (int j = 0; j < 4; j++) {
            #pragma unroll
            for (int rg = 0; rg < 4; rg++) {
                const size_t m = m0 + wm * 64 + i * 16 + quad * 4 + rg;
                const int nl = wn * 64 + j * 16 + col;
                gx[m * 1024 + (size_t)wgy * 128 + nl] = (f16)(acc[i][j][rg] + bias_lds[nl]);
            }
        }
    }
}

// ---------------------------------------------------------------------------
// Kernel 2: batch-packed recurrence, 4-way unit split + wave specialization.
// 32 WGs x 512 thr (1 WG/CU, trivially co-resident). WG (g = blk&7, j =
// blk>>3): batch-group g (16 batches), units [64j, 64j+64), all 4 gates.
// Compute waves 0-3: wave w owns unit-block u = 64j+16w+l15; 4 tiles
// (f,i,c,o) x 8-kt chain = 32 MFMA/wave/step (~620 cyc/SIMD matrix-pipe,
// half of round-1). Lane holds (4 batches x 1 unit x 4 gates) IN REGISTERS
// -> elementwise fully lane-local, no gates LDS roundtrip. Exchange waves
// 4-7: poll the 3 peer WGs' tagged words (12/thread, done-mask: matched
// words never re-loaded; s_sleep backoff) and stage into hbuf[ns] WHILE the
// compute waves crunch step t — the LLC round trip (agent atomics are
// LLC-serviced; round-2 lesson) hides under ~900 cyc of compute. One
// barrier per step.
//
// Mailbox: per group [2 slots][256 units][16 batches] tagged (h<<16)|(t+1),
// relaxed agent atomics. Reuse induction (2 slots): A overwrites tag t+1
// with t+3 only after A staged t+2, which needed every peer's t+2 publish,
// which is after that peer staged t+1 (read A's t+1 words). Zeroed by
// gemm_gx each replay; spin bounded so a bug can't hang the GPU.
// hbuf rows padded to 264 f16 (528 B = 33*16: b128-aligned, bank-rotating)
// -> <=2-way LDS conflicts without swizzle VALU.
// ---------------------------------------------------------------------------
__global__ __launch_bounds__(512, 2) void lstm_rec(
    const float* __restrict__ Wf, const float* __restrict__ Wi,
    const float* __restrict__ Wc, const float* __restrict__ Wo,
    const f16* __restrict__ gx,
    const float* __restrict__ Wout, const float* __restrict__ bout,
    u32* hx,
    float* __restrict__ out) {
    __shared__ _Float16 hbuf[2][16][264] __attribute__((aligned(16)));

    const int tid  = threadIdx.x;
    const int bb   = blockIdx.x;
    const int g    = bb & 7;          // batch-group -> XCD g (locality only)
    const int j    = bb >> 3;         // unit-quarter 0..3
    const int w    = tid >> 6;        // wave
    const int l    = tid & 63;
    const int l15  = l & 15;
    const int quad = l >> 4;

    u32* mail = hx + (size_t)g * 2 * 4096;   // [slot][u_abs(256)][b(16)]

    // zero hbuf[0] (h_0 = 0)
    {
        _Float16* hz = &hbuf[0][0][0];
        for (int idx = tid; idx < 16 * 264; idx += 512) hz[idx] = (f16)0.0f;
    }

    // ---- compute-wave state ----
    const int u_abs = j * 64 + w * 16 + l15;     // valid for w<4
    f16x8v wB[4][8];
    const f16* gxp[4];
    float pg_[4][4];
    float c4[4] = {0.f, 0.f, 0.f, 0.f};

    // ---- exchange-wave state ----
    int   x_uabs[12];
    int   x_moff[12];
    int   x_be = 0;

    if (w < 4) {
        const float* gp[4] = {Wf, Wi, Wc, Wo};
        #pragma unroll
        for (int gt = 0; gt < 4; gt++) {
            const float* row = gp[gt] + (size_t)u_abs * 512 + 256 + quad * 8;
            #pragma unroll
            for (int kt = 0; kt < 8; kt++) {
                float4 x0 = *(const float4*)(row + kt * 32);
                float4 x1 = *(const float4*)(row + kt * 32 + 4);
                wB[gt][kt] = pack8(x0, x1);
            }
        }
        const int b0 = g * 16 + quad * 4;
        #pragma unroll
        for (int r = 0; r < 4; r++) {
            gxp[r] = gx + ((size_t)(b0 + r) * 512) * 1024 + u_abs;
            #pragma unroll
            for (int gt = 0; gt < 4; gt++)
                pg_[r][gt] = (float)gxp[r][gt * 256];   // t = 0
        }
    } else {
        const int e  = (w - 4) * 64 + l;   // 0..255
        x_be = e & 15;                     // local batch column
        const int rb = e >> 4;             // 0..15
        #pragma unroll
        for (int k = 0; k < 12; k++) {
            const int ru = rb * 12 + k;                    // 0..191 remote
            const int ua = ru + (ru >= j * 64 ? 64 : 0);   // skip own quarter
            x_uabs[k] = ua;
            x_moff[k] = ua * 16 + x_be;
        }
    }

    const f32x4 Zc = {0.f, 0.f, 0.f, 0.f};

    __syncthreads();   // h_0 visible

    int cur = 0;
    for (int t = 0; t < 512; t++) {
        const int ns = (t + 1) & 1;

        if (w < 4) {
            // issue next step's gx loads early (used next iteration)
            float pn[4][4];
            const size_t toff = (size_t)(t < 511 ? t + 1 : 511) * 1024;
            #pragma unroll
            for (int r = 0; r < 4; r++)
                #pragma unroll
                for (int gt = 0; gt < 4; gt++)
                    pn[r][gt] = (float)gxp[r][toff + gt * 256];

            // gates for this wave's 16 units x 4 gates: H[16,256] @ W^T
            f32x4 acc[4];
            #pragma unroll
            for (int kt = 0; kt < 8; kt++) {
                f16x8v A = *(const f16x8v*)&hbuf[cur][l15][kt * 32 + quad * 8];
                if (kt == 0) {
                    #pragma unroll
                    for (int gt = 0; gt < 4; gt++)
                        acc[gt] = __builtin_amdgcn_mfma_f32_16x16x32_f16(A, wB[gt][0], Zc, 0, 0, 0);
                } else {
                    #pragma unroll
                    for (int gt = 0; gt < 4; gt++)
                        acc[gt] = __builtin_amdgcn_mfma_f32_16x16x32_f16(A, wB[gt][kt], acc[gt], 0, 0, 0);
                }
            }

            // lane-local elementwise: cell (batch = quad*4+r, unit = u_abs)
            u32* sp = mail + (size_t)ns * 4096 + u_abs * 16 + quad * 4;
            #pragma unroll
            for (int r = 0; r < 4; r++) {
                float F = pg_[r][0] + acc[0][r];
                float I = pg_[r][1] + acc[1][r];
                float G = pg_[r][2] + acc[2][r];
                float O = pg_[r][3] + acc[3][r];
                float sf = sigm(F), si = sigm(I), so = sigm(O);
                float tg = tanh_f(G);
                c4[r] = c4[r] * sf + si * tg;
                float h = tanh_f(c4[r]) * so;
                const f16 h16v = (f16)h;
                u32 word = ((u32)__builtin_bit_cast(unsigned short, h16v) << 16)
                         | (u32)(t + 1);
                __hip_atomic_store(sp + r, word, __ATOMIC_RELAXED,
                                   __HIP_MEMORY_SCOPE_AGENT);
                hbuf[ns][quad * 4 + r][u_abs] = h16v;   // own quarter into LDS
            }
            #pragma unroll
            for (int r = 0; r < 4; r++)
                #pragma unroll
                for (int gt = 0; gt < 4; gt++)
                    pg_[r][gt] = pn[r][gt];
        } else {
            // exchange waves: gather the 3 remote quarters for step t+1
            u32* sp = mail + (size_t)ns * 4096;
            _Float16* hrow = &hbuf[ns][x_be][0];
            const u32 want = (u32)(t + 1);
            u32 done = 0;
            int spin = 0;
            for (;;) {
                #pragma unroll
                for (int k = 0; k < 12; k++) {
                    if (!(done & (1u << k))) {
                        u32 wd = __hip_atomic_load(sp + x_moff[k], __ATOMIC_RELAXED,
                                                   __HIP_MEMORY_SCOPE_AGENT);
                        if ((wd & 0xFFFFu) == want) {
                            hrow[x_uabs[k]] =
                                __builtin_bit_cast(_Float16, (unsigned short)(wd >> 16));
                            done |= 1u << k;
                        }
                    }
                }
                if (done == 0xFFFu) break;
                if (++spin > 4096) break;          // bound: never hang
                __builtin_amdgcn_s_sleep(2);       // throttle LLC poll traffic
            }
        }

        __syncthreads();   // h_{t+1} fully staged; guards hbuf slot reuse
        cur = ns;
    }

    // out[b, 32j:32j+32] = h_512 @ Wout^T + bout  (h_512 in hbuf[0])
    {
        const int b_loc = tid >> 5;        // 0..15
        const int o     = j * 32 + (tid & 31);
        float accv = bout[o];
        const _Float16* hr = &hbuf[0][b_loc][0];
        const float* wr = Wout + (size_t)o * 256;
        for (int k0 = 0; k0 < 256; k0 += 8) {
            f16x8v hv = *(const f16x8v*)&hr[k0];
            float4 w0 = *(const float4*)(wr + k0);
            float4 w1 = *(const float4*)(wr + k0 + 4);
            accv += w0.x * (float)hv[0] + w0.y * (float)hv[1]
                  + w0.z * (float)hv[2] + w0.w * (float)hv[3]
                  + w1.x * (float)hv[4] + w1.y * (float)hv[5]
                  + w1.z * (float)hv[6] + w1.w * (float)hv[7];
        }
        out[(size_t)(g * 16 + b_loc) * 128 + o] = accv;
    }
}

extern "C" void kernel_launch(void* const* d_in, const int* in_sizes, int n_in,
                              void* d_out, int out_size, void* d_ws, size_t ws_size,
                              hipStream_t stream) {
    const float* x    = (const float*)d_in[0];
    const float* Wf   = (const float*)d_in[1];
    const float* bfv  = (const float*)d_in[2];
    const float* Wi   = (const float*)d_in[3];
    const float* biv  = (const float*)d_in[4];
    const float* Wc   = (const float*)d_in[5];
    const float* bcv  = (const float*)d_in[6];
    const float* Wo   = (const float*)d_in[7];
    const float* bov  = (const float*)d_in[8];
    const float* Wout = (const float*)d_in[9];
    const float* bout = (const float*)d_in[10];

    f16* gx = (f16*)d_ws;
    u32* hx = (u32*)((char*)d_ws + GX_BYTES);   // 256 KB mailbox after gx

    gemm_gx<<<dim3(512, 8), 256, 0, stream>>>(x, Wf, Wi, Wc, Wo, bfv, biv, bcv, bov, gx, hx);
    lstm_rec<<<32, 512, 0, stream>>>(Wf, Wi, Wc, Wo, gx, Wout, bout, hx, (float*)d_out);
}